// Round 13
// baseline (1436.869 us; speedup 1.0000x reference)
//
#include <hip/hip_runtime.h>
#include <hip/hip_bf16.h>

using bf16 = __hip_bfloat16;
typedef __attribute__((ext_vector_type(8))) short short8;
typedef __attribute__((ext_vector_type(4))) short short4v;
typedef __attribute__((ext_vector_type(4))) float f32x4;
typedef __attribute__((ext_vector_type(2))) float f32x2;

__device__ __forceinline__ float bfbits2f(unsigned short h) {
    unsigned v = (unsigned)h << 16;
    return __uint_as_float(v);
}

__device__ __forceinline__ void gload16(const void* g, void* l) {
    __builtin_amdgcn_global_load_lds(
        (const __attribute__((address_space(1))) unsigned int*)g,
        (__attribute__((address_space(3))) unsigned int*)l, 16, 0, 0);
}

// tanh-form GELU: ~8 VALU; |diff vs exact erf-GELU| <= ~3e-3
__device__ __forceinline__ float gelu_fast(float x) {
    float x2 = x * x;
    float u = x * __builtin_fmaf(0.07135481f, x2, 1.59576912f);
    float e = __expf(u);
    return x - x * __builtin_amdgcn_rcpf(e + 1.0f);
}

__device__ __forceinline__ float wave_sum(float v) {
#pragma unroll
    for (int o = 32; o > 0; o >>= 1) v += __shfl_xor(v, o, 64);
    return v;
}

// ---- LayerNorm over D=768: one WAVE per token; also emits bf16 copy of x ----
__global__ __launch_bounds__(256) void ln_f32(const float* __restrict__ x,
                                              const float* __restrict__ g,
                                              const float* __restrict__ b,
                                              bf16* __restrict__ y,
                                              bf16* __restrict__ xb) {
    int wave = threadIdx.x >> 6, lane = threadIdx.x & 63;
    size_t base = ((size_t)blockIdx.x * 4 + wave) * 768;
    int c0 = lane * 4;
    float4 v0 = *(const float4*)&x[base + c0];
    float4 v1 = *(const float4*)&x[base + 256 + c0];
    float4 v2 = *(const float4*)&x[base + 512 + c0];
    float raw[12] = {v0.x, v0.y, v0.z, v0.w, v1.x, v1.y, v1.z, v1.w,
                     v2.x, v2.y, v2.z, v2.w};
#pragma unroll
    for (int j = 0; j < 3; j++) {
        short4v o;
#pragma unroll
        for (int u = 0; u < 4; u++)
            o[u] = (short)__bfloat16_as_ushort(__float2bfloat16(raw[j * 4 + u]));
        *(short4v*)&((unsigned short*)xb)[base + j * 256 + c0] = o;
    }
    float s = wave_sum(v0.x + v0.y + v0.z + v0.w + v1.x + v1.y + v1.z + v1.w +
                       v2.x + v2.y + v2.z + v2.w);
    float mean = s * (1.0f / 768.0f);
    float d[12];
#pragma unroll
    for (int i = 0; i < 12; i++) d[i] = raw[i] - mean;
    float sq = 0.f;
#pragma unroll
    for (int i = 0; i < 12; i++) sq += d[i] * d[i];
    sq = wave_sum(sq);
    float rstd = rsqrtf(sq * (1.0f / 768.0f) + 1e-6f);
#pragma unroll
    for (int j = 0; j < 3; j++) {
        float4 gv = *(const float4*)&g[j * 256 + c0];
        float4 bv = *(const float4*)&b[j * 256 + c0];
        short4v o;
        o[0] = (short)__bfloat16_as_ushort(__float2bfloat16(d[j * 4 + 0] * rstd * gv.x + bv.x));
        o[1] = (short)__bfloat16_as_ushort(__float2bfloat16(d[j * 4 + 1] * rstd * gv.y + bv.y));
        o[2] = (short)__bfloat16_as_ushort(__float2bfloat16(d[j * 4 + 2] * rstd * gv.z + bv.z));
        o[3] = (short)__bfloat16_as_ushort(__float2bfloat16(d[j * 4 + 3] * rstd * gv.w + bv.w));
        *(short4v*)&((unsigned short*)y)[base + j * 256 + c0] = o;
    }
}

// ---- LayerNorm, bf16 in -> bf16 out (wave-per-token) ----
__global__ __launch_bounds__(256) void ln_bf(const bf16* __restrict__ x,
                                             const float* __restrict__ g,
                                             const float* __restrict__ b,
                                             bf16* __restrict__ y) {
    int wave = threadIdx.x >> 6, lane = threadIdx.x & 63;
    size_t base = ((size_t)blockIdx.x * 4 + wave) * 768;
    int c0 = lane * 4;
    float d[12];
#pragma unroll
    for (int j = 0; j < 3; j++) {
        short4v w = *(const short4v*)&((const unsigned short*)x)[base + j * 256 + c0];
#pragma unroll
        for (int u = 0; u < 4; u++) d[j * 4 + u] = bfbits2f((unsigned short)w[u]);
    }
    float s = 0.f;
#pragma unroll
    for (int i = 0; i < 12; i++) s += d[i];
    s = wave_sum(s);
    float mean = s * (1.0f / 768.0f);
    float sq = 0.f;
#pragma unroll
    for (int i = 0; i < 12; i++) { d[i] -= mean; sq += d[i] * d[i]; }
    sq = wave_sum(sq);
    float rstd = rsqrtf(sq * (1.0f / 768.0f) + 1e-6f);
#pragma unroll
    for (int j = 0; j < 3; j++) {
        float4 gv = *(const float4*)&g[j * 256 + c0];
        float4 bv = *(const float4*)&b[j * 256 + c0];
        short4v o;
        o[0] = (short)__bfloat16_as_ushort(__float2bfloat16(d[j * 4 + 0] * rstd * gv.x + bv.x));
        o[1] = (short)__bfloat16_as_ushort(__float2bfloat16(d[j * 4 + 1] * rstd * gv.y + bv.y));
        o[2] = (short)__bfloat16_as_ushort(__float2bfloat16(d[j * 4 + 2] * rstd * gv.z + bv.z));
        o[3] = (short)__bfloat16_as_ushort(__float2bfloat16(d[j * 4 + 3] * rstd * gv.w + bv.w));
        *(short4v*)&((unsigned short*)y)[base + j * 256 + c0] = o;
    }
}

// ---- fused prep: weight casts (+KQV pad-zero) + bias concat, one launch ----
__global__ __launch_bounds__(256) void prep(
    const float* __restrict__ Wk, const float* __restrict__ Wq,
    const float* __restrict__ Wv, const float* __restrict__ Wr,
    const float* __restrict__ W1, const float* __restrict__ W2,
    const float* __restrict__ bk, const float* __restrict__ bq,
    const float* __restrict__ bv,
    bf16* __restrict__ Wkqv, bf16* __restrict__ Wrb,
    bf16* __restrict__ W1b, bf16* __restrict__ W2b, float* __restrict__ bkqv) {
    int i = blockIdx.x * 256 + threadIdx.x;
    const int nKQV = 2048 * 768, nWr = 768 * 384, nW1 = 3072 * 768, nW2 = 768 * 3072;
    if (i < nKQV) {
        int r = i / 768;
        float v = 0.f;
        if (r < 768) v = Wk[i];
        else if (r < 1536) v = Wq[i - 768 * 768];
        else if (r < 1920) v = Wv[i - 1536 * 768];
        Wkqv[i] = __float2bfloat16(v);
        return;
    }
    i -= nKQV;
    if (i < nWr) { Wrb[i] = __float2bfloat16(Wr[i]); return; }
    i -= nWr;
    if (i < nW1) { W1b[i] = __float2bfloat16(W1[i]); return; }
    i -= nW1;
    if (i < nW2) { W2b[i] = __float2bfloat16(W2[i]); return; }
    i -= nW2;
    if (i < 1920) bkqv[i] = (i < 768) ? bk[i] : (i < 1536 ? bq[i - 768] : bv[i - 1536]);
}

// ---- bf16 transpose per batch: Y [768,3136] -> Xt [3136,768] ----
__global__ __launch_bounds__(256) void transp_k(const bf16* __restrict__ Y,
                                                bf16* __restrict__ Xt) {
    __shared__ unsigned short tile[64][65];
    const size_t LD = (size_t)768 * 3136;
    int n = blockIdx.z;
    int l0 = blockIdx.x * 64, d0 = blockIdx.y * 64;
    const unsigned short* Yp = (const unsigned short*)Y + (size_t)n * LD;
    unsigned short* Xp = (unsigned short*)Xt + (size_t)n * LD;
    int t = threadIdx.x;
#pragma unroll
    for (int j = 0; j < 2; j++) {
        int e = t + 256 * j;
        int dd = e >> 3, lg = (e & 7) * 8;
        short8 v = *(const short8*)&Yp[(size_t)(d0 + dd) * 3136 + l0 + lg];
#pragma unroll
        for (int u = 0; u < 8; u++) tile[dd][lg + u] = (unsigned short)v[u];
    }
    __syncthreads();
#pragma unroll
    for (int j = 0; j < 2; j++) {
        int e = t + 256 * j;
        int ll = e >> 3, dg = (e & 7) * 8;
        short8 v;
#pragma unroll
        for (int u = 0; u < 8; u++) v[u] = (short)tile[dg + u][ll];
        *(short8*)&Xp[(size_t)(l0 + ll) * 768 + d0 + dg] = v;
    }
}

// ====== 256x256 BK=64 GEMM, 4-phase/tile interleave + counted vmcnt ======
// Schedule byte-identical to R9-R12.
// MODE 0: split-KQV bf16 (N padded; store col<1920), +bias[col]
// MODE 1: C0=bf16, v + bias[col] + residb(bf16)[flat]  (Wr; resid aliases C0)
// MODE 2: C0=bf16, gelu(v + bias[col])
// MODE 3: C0=f32,  v + bias[col] + residb(bf16)[flat]
template <int MODE>
__global__ __launch_bounds__(512, 2) void gemm256(
    const bf16* __restrict__ A, const bf16* __restrict__ B,
    const float* __restrict__ bias, const void* __restrict__ resid,
    void* __restrict__ C0, void* __restrict__ C1, void* __restrict__ C2,
    int M, int N, int K) {
    extern __shared__ char smem[];
    const int tid = threadIdx.x;
    const int lane = tid & 63, wave = tid >> 6;

    const int nbn = gridDim.x;
    const int nwg = nbn * gridDim.y;
    const int orig = blockIdx.y * nbn + blockIdx.x;
    const int qq = nwg >> 3, rm = nwg & 7;
    const int xcd = orig & 7, pos = orig >> 3;
    const int work = (xcd < rm ? xcd * (qq + 1) : rm * (qq + 1) + (xcd - rm) * qq) + pos;
    const int bn = work % nbn, bm = work / nbn;

    const int wm = (wave >> 2) * 128, wn = (wave & 3) * 64;
    const int frow = lane & 15, fsb = lane >> 4;
    const int rslot = (fsb ^ ((frow >> 1) & 3)) * 16;
    const int srowS = lane >> 2;
    const int sslotS = (lane & 3) ^ ((lane >> 3) & 3);
    const size_t rowB = (size_t)K * 2;
    const char* ApS = (const char*)A + (size_t)(bm * 256 + wave * 32 + srowS) * rowB + sslotS * 16;
    const char* BpS = (const char*)B + (size_t)(bn * 256 + wave * 32 + srowS) * rowB + sslotS * 16;

    f32x4 acc[8][4];
#pragma unroll
    for (int mi = 0; mi < 8; mi++)
#pragma unroll
        for (int ni = 0; ni < 4; ni++)
#pragma unroll
            for (int r = 0; r < 4; r++) acc[mi][ni][r] = 0.0f;

    auto stA = [&](int t, int k2) {
        char* d = smem + (t & 1) * 65536 + k2 * 16384 + wave * 2048;
        const char* s = ApS + (size_t)t * 128 + k2 * 64;
        gload16(s, d);
        gload16(s + (size_t)16 * rowB, d + 1024);
    };
    auto stB = [&](int t, int k2) {
        char* d = smem + (t & 1) * 65536 + 32768 + k2 * 16384 + wave * 2048;
        const char* s = BpS + (size_t)t * 128 + k2 * 64;
        gload16(s, d);
        gload16(s + (size_t)16 * rowB, d + 1024);
    };

    const int nt = K >> 6;
    stA(0, 0); stB(0, 0); stA(0, 1); stB(0, 1);
    stA(1, 0); stB(1, 0);
    asm volatile("s_waitcnt vmcnt(8)" ::: "memory");
    __builtin_amdgcn_s_barrier();
    asm volatile("" ::: "memory");

    for (int t = 0; t < nt; ++t) {
        const char* base = smem + (t & 1) * 65536;
        short8 bfv[4], af[4];
        // ---------- phase 0: k2=0, M-low ----------
#pragma unroll
        for (int ni = 0; ni < 4; ni++)
            bfv[ni] = *(const short8*)(base + 32768 + (wn + ni * 16 + frow) * 64 + rslot);
#pragma unroll
        for (int i = 0; i < 4; i++)
            af[i] = *(const short8*)(base + (wm + i * 16 + frow) * 64 + rslot);
        if (t + 1 < nt) stA(t + 1, 1);
        asm volatile("" ::: "memory");
        __builtin_amdgcn_s_barrier();
        asm volatile("" ::: "memory");
        __builtin_amdgcn_s_setprio(1);
#pragma unroll
        for (int i = 0; i < 4; i++)
#pragma unroll
            for (int ni = 0; ni < 4; ni++)
                acc[i][ni] = __builtin_amdgcn_mfma_f32_16x16x32_bf16(
                    af[i], bfv[ni], acc[i][ni], 0, 0, 0);
        __builtin_amdgcn_s_setprio(0);
        asm volatile("" ::: "memory");
        __builtin_amdgcn_s_barrier();
        asm volatile("" ::: "memory");
        // ---------- phase 1: k2=0, M-high ----------
#pragma unroll
        for (int i = 0; i < 4; i++)
            af[i] = *(const short8*)(base + (wm + (4 + i) * 16 + frow) * 64 + rslot);
        if (t + 1 < nt) stB(t + 1, 1);
        asm volatile("" ::: "memory");
        __builtin_amdgcn_s_barrier();
        asm volatile("" ::: "memory");
        __builtin_amdgcn_s_setprio(1);
#pragma unroll
        for (int i = 0; i < 4; i++)
#pragma unroll
            for (int ni = 0; ni < 4; ni++)
                acc[4 + i][ni] = __builtin_amdgcn_mfma_f32_16x16x32_bf16(
                    af[i], bfv[ni], acc[4 + i][ni], 0, 0, 0);
        __builtin_amdgcn_s_setprio(0);
        if (t == nt - 1)
            asm volatile("s_waitcnt vmcnt(0)" ::: "memory");
        else
            asm volatile("s_waitcnt vmcnt(8)" ::: "memory");
        __builtin_amdgcn_s_barrier();
        asm volatile("" ::: "memory");
        // ---------- phase 2: k2=1, M-low ----------
#pragma unroll
        for (int ni = 0; ni < 4; ni++)
            bfv[ni] = *(const short8*)(base + 32768 + 16384 + (wn + ni * 16 + frow) * 64 + rslot);
#pragma unroll
        for (int i = 0; i < 4; i++)
            af[i] = *(const short8*)(base + 16384 + (wm + i * 16 + frow) * 64 + rslot);
        if (t + 2 < nt) stA(t + 2, 0);
        asm volatile("" ::: "memory");
        __builtin_amdgcn_s_barrier();
        asm volatile("" ::: "memory");
        __builtin_amdgcn_s_setprio(1);
#pragma unroll
        for (int i = 0; i < 4; i++)
#pragma unroll
            for (int ni = 0; ni < 4; ni++)
                acc[i][ni] = __builtin_amdgcn_mfma_f32_16x16x32_bf16(
                    af[i], bfv[ni], acc[i][ni], 0, 0, 0);
        __builtin_amdgcn_s_setprio(0);
        asm volatile("" ::: "memory");
        __builtin_amdgcn_s_barrier();
        asm volatile("" ::: "memory");
        // ---------- phase 3: k2=1, M-high ----------
#pragma unroll
        for (int i = 0; i < 4; i++)
            af[i] = *(const short8*)(base + 16384 + (wm + (4 + i) * 16 + frow) * 64 + rslot);
        if (t + 2 < nt) stB(t + 2, 0);
        asm volatile("" ::: "memory");
        __builtin_amdgcn_s_barrier();
        asm volatile("" ::: "memory");
        __builtin_amdgcn_s_setprio(1);
#pragma unroll
        for (int i = 0; i < 4; i++)
#pragma unroll
            for (int ni = 0; ni < 4; ni++)
                acc[4 + i][ni] = __builtin_amdgcn_mfma_f32_16x16x32_bf16(
                    af[i], bfv[ni], acc[4 + i][ni], 0, 0, 0);
        __builtin_amdgcn_s_setprio(0);
        if (t + 1 < nt) {
            if (t + 1 == nt - 1)
                asm volatile("s_waitcnt vmcnt(4)" ::: "memory");
            else
                asm volatile("s_waitcnt vmcnt(8)" ::: "memory");
        }
        __builtin_amdgcn_s_barrier();
        asm volatile("" ::: "memory");
    }

    const unsigned short* Rb = (const unsigned short*)resid;
#pragma unroll
    for (int mi = 0; mi < 8; mi++)
#pragma unroll
        for (int ni = 0; ni < 4; ni++)
#pragma unroll
            for (int r = 0; r < 4; r++) {
                int row = bm * 256 + wm + mi * 16 + (lane >> 4) * 4 + r;
                int col = bn * 256 + wn + ni * 16 + frow;
                float v = acc[mi][ni][r];
                if (MODE == 0) {
                    if (col < 1920) {
                        float o = v + bias[col];
                        if (col < 768)
                            ((bf16*)C0)[(size_t)row * 768 + col] = __float2bfloat16(o);
                        else if (col < 1536)
                            ((bf16*)C1)[(size_t)row * 768 + col - 768] = __float2bfloat16(o);
                        else
                            ((bf16*)C2)[(size_t)row * 384 + col - 1536] = __float2bfloat16(o);
                    }
                } else if (MODE == 1) {
                    size_t idx = (size_t)row * N + col;
                    ((bf16*)C0)[idx] =
                        __float2bfloat16(v + bias[col] + bfbits2f(Rb[idx]));
                } else if (MODE == 2) {
                    ((bf16*)C0)[(size_t)row * N + col] =
                        __float2bfloat16(gelu_fast(v + bias[col]));
                } else {
                    size_t idx = (size_t)row * N + col;
                    ((float*)C0)[idx] = v + bias[col] + bfbits2f(Rb[idx]);
                }
            }
}

// ---- fused context: ctx_raw[nh,96,48] = sum_l exp(k[l,96]) outer v[l,48];
//      S[nh,96] = sum_l exp(k). Grid (14, 128): 224 l's per block.
//      Regrouped (32kg x 3k) x (8vg x 6v): 6 LDS reads/l, 9 pk-FMAs/l. ----
__global__ __launch_bounds__(256) void context_k(const bf16* __restrict__ Kt,
                                                 const bf16* __restrict__ Vt,
                                                 float* __restrict__ ctx,
                                                 float* __restrict__ Sf) {
    __shared__ float ks[32][96];
    __shared__ float vs[32][48];
    int nh = blockIdx.y;
    int n = nh >> 3, h = nh & 7;
    int t = threadIdx.x;
    const unsigned short* kp = (const unsigned short*)Kt;
    const unsigned short* vp = (const unsigned short*)Vt;
    int kg = t >> 3, vg = t & 7;       // k = kg*3+i (i<3), v = vg*6+2u+e (u<3)
    f32x2 acc2[3][3];
    float sacc[3];
#pragma unroll
    for (int i = 0; i < 3; i++) {
        sacc[i] = 0.f;
#pragma unroll
        for (int u = 0; u < 3; u++) { acc2[i][u][0] = 0.f; acc2[i][u][1] = 0.f; }
    }
    int l0 = blockIdx.x * 224;
    for (int ls = l0; ls < l0 + 224; ls += 32) {
        __syncthreads();
#pragma unroll
        for (int j = 0; j < 6; j++) {
            int e = t + 256 * j;
            int row = e / 48, cp = e % 48;
            unsigned u = *(const unsigned*)&kp[((size_t)(n * 3136 + ls + row)) * 768 + h * 96 + cp * 2];
            ks[row][cp * 2] = __expf(bfbits2f((unsigned short)(u & 0xffff)));
            ks[row][cp * 2 + 1] = __expf(bfbits2f((unsigned short)(u >> 16)));
        }
#pragma unroll
        for (int j = 0; j < 3; j++) {
            int e = t + 256 * j;
            int row = e / 24, cp = e % 24;
            unsigned u = *(const unsigned*)&vp[((size_t)(n * 3136 + ls + row)) * 384 + h * 48 + cp * 2];
            vs[row][cp * 2] = bfbits2f((unsigned short)(u & 0xffff));
            vs[row][cp * 2 + 1] = bfbits2f((unsigned short)(u >> 16));
        }
        __syncthreads();
        for (int ll = 0; ll < 32; ll++) {
            float kv[3];
            f32x2 vv2[3];
#pragma unroll
            for (int i = 0; i < 3; i++) kv[i] = ks[ll][kg * 3 + i];
#pragma unroll
            for (int u = 0; u < 3; u++)
                vv2[u] = *(const f32x2*)&vs[ll][vg * 6 + u * 2];
#pragma unroll
            for (int i = 0; i < 3; i++) {
                sacc[i] += kv[i];
                f32x2 kk = {kv[i], kv[i]};
#pragma unroll
                for (int u = 0; u < 3; u++) acc2[i][u] += vv2[u] * kk;
            }
        }
    }
    float* cb = ctx + (size_t)nh * 4608;
#pragma unroll
    for (int i = 0; i < 3; i++) {
#pragma unroll
        for (int u = 0; u < 3; u++) {
            atomicAdd(&cb[(kg * 3 + i) * 48 + vg * 6 + u * 2], acc2[i][u][0]);
            atomicAdd(&cb[(kg * 3 + i) * 48 + vg * 6 + u * 2 + 1], acc2[i][u][1]);
        }
        if (vg == 0) atomicAdd(&Sf[(size_t)nh * 96 + kg * 3 + i], sacc[i]);
    }
}

// ---- att: normalize ctx by S while loading to LDS, per-token softmax(q),
//      then ctx^T @ q via packed-f32 FMAs, COMPACT bf16 out [50176, 384] ----
__global__ __launch_bounds__(256) void att_k(const float* __restrict__ ctx,
                                             const float* __restrict__ Sf,
                                             const bf16* __restrict__ Qt,
                                             bf16* __restrict__ att) {
    __shared__ float cs[4608];
    __shared__ float sinv[96];
    int nh = blockIdx.y;
    int n = nh >> 3, h = nh & 7;
    if (threadIdx.x < 96)
        sinv[threadIdx.x] = 1.0f / Sf[(size_t)nh * 96 + threadIdx.x];
    __syncthreads();
    for (int j = threadIdx.x; j < 4608; j += 256)
        cs[j] = ctx[(size_t)nh * 4608 + j] * sinv[j / 48];
    __syncthreads();
    int l = blockIdx.x * 256 + threadIdx.x;
    if (l >= 3136) return;
    const unsigned short* qp = (const unsigned short*)Qt + ((size_t)(n * 3136 + l)) * 768 + h * 96;
    float qv[96];
    float s = 0.f;
#pragma unroll
    for (int j = 0; j < 12; j++) {
        short8 w = *(const short8*)&qp[j * 8];
#pragma unroll
        for (int x = 0; x < 8; x++) {
            float e = __expf(bfbits2f((unsigned short)w[x]));
            qv[j * 8 + x] = e;
            s += e;
        }
    }
    float inv = 1.0f / s;
    unsigned short ov[48];
#pragma unroll
    for (int vb = 0; vb < 12; vb++) {
        f32x2 a0 = {0.f, 0.f}, a1 = {0.f, 0.f};
        for (int k = 0; k < 96; k++) {
            f32x4 c4 = *(const f32x4*)&cs[k * 48 + vb * 4];
            float q = qv[k];
            f32x2 qq = {q, q};
            f32x2 lo = __builtin_shufflevector(c4, c4, 0, 1);
            f32x2 hi = __builtin_shufflevector(c4, c4, 2, 3);
            a0 += lo * qq;   // v_pk_fma_f32
            a1 += hi * qq;
        }
        ov[vb * 4 + 0] = __bfloat16_as_ushort(__float2bfloat16(a0[0] * inv));
        ov[vb * 4 + 1] = __bfloat16_as_ushort(__float2bfloat16(a0[1] * inv));
        ov[vb * 4 + 2] = __bfloat16_as_ushort(__float2bfloat16(a1[0] * inv));
        ov[vb * 4 + 3] = __bfloat16_as_ushort(__float2bfloat16(a1[1] * inv));
    }
    unsigned short* op = (unsigned short*)att + ((size_t)(n * 3136 + l)) * 384 + h * 48;
#pragma unroll
    for (int j = 0; j < 6; j++) *(short8*)&op[j * 8] = *(short8*)&ov[j * 8];
}

extern "C" void kernel_launch(void* const* d_in, const int* in_sizes, int n_in,
                              void* d_out, int out_size, void* d_ws, size_t ws_size,
                              hipStream_t stream) {
    (void)in_sizes; (void)n_in; (void)out_size; (void)ws_size;
    const float* x     = (const float*)d_in[0];
    const float* ln1_g = (const float*)d_in[1];
    const float* ln1_b = (const float*)d_in[2];
    const float* Wk    = (const float*)d_in[3];
    const float* bk    = (const float*)d_in[4];
    const float* Wq    = (const float*)d_in[5];
    const float* bq    = (const float*)d_in[6];
    const float* Wv    = (const float*)d_in[7];
    const float* bv    = (const float*)d_in[8];
    const float* Wr    = (const float*)d_in[9];
    const float* br    = (const float*)d_in[10];
    const float* ln2_g = (const float*)d_in[11];
    const float* ln2_b = (const float*)d_in[12];
    const float* W1    = (const float*)d_in[13];
    const float* b1    = (const float*)d_in[14];
    const float* W2    = (const float*)d_in[15];
    const float* b2    = (const float*)d_in[16];

    const size_t sz77 = (size_t)50176 * 768 * 2;

    char* w = (char*)d_ws;
    size_t off = 0;
    auto alloc = [&](size_t bytes) {
        char* p = w + off;
        off = (off + bytes + 255) & ~(size_t)255;
        return p;
    };
    bf16* Ybf  = (bf16*)alloc(sz77);                       // Hbf rgn 0
    bf16* Xt   = (bf16*)alloc(sz77);                       // Hbf rgn 1 (ctx/S alias)
    bf16* Kt   = (bf16*)alloc(sz77);                       // Hbf rgn 2
    bf16* Qt   = (bf16*)alloc(sz77);                       // Hbf rgn 3
    bf16* Vt   = (bf16*)alloc((size_t)50176 * 384 * 2);    // Y2bf rgn (front)
    bf16* attb = (bf16*)alloc((size_t)50176 * 384 * 2);    // Y2bf rgn (back)
    bf16* x1   = (bf16*)alloc(sz77);                       // bf16(x) until Wr overwrites
    bf16* Wkqv_bf = (bf16*)alloc((size_t)2048 * 768 * 2);  // padded to 2048 rows
    bf16* Wr_bf = (bf16*)alloc((size_t)768 * 384 * 2);
    bf16* W1_bf = (bf16*)alloc((size_t)3072 * 768 * 2);
    bf16* W2_bf = (bf16*)alloc((size_t)768 * 3072 * 2);
    float* bkqv = (float*)alloc((size_t)1920 * 4);
    // ctx + S alias Xt (Xt dead after KQV gemm; region dead before MLP1)
    float* ctx = (float*)Xt;
    float* Sf  = (float*)((char*)Xt + 2359296);   // right after ctx (2,359,296 B)
    bf16* Hbf  = Ybf;    // [50176,3072] spans rgns 0-3
    bf16* Y2bf = Vt;     // spans Vt+attb exactly

    // fused weight-cast + pad + bias-concat (one launch)
    prep<<<25736, 256, 0, stream>>>(Wk, Wq, Wv, Wr, W1, W2, bk, bq, bv,
                                    Wkqv_bf, Wr_bf, W1_bf, W2_bf, bkqv);

    hipFuncSetAttribute((const void*)gemm256<0>,
                        hipFuncAttributeMaxDynamicSharedMemorySize, 131072);
    hipFuncSetAttribute((const void*)gemm256<1>,
                        hipFuncAttributeMaxDynamicSharedMemorySize, 131072);
    hipFuncSetAttribute((const void*)gemm256<2>,
                        hipFuncAttributeMaxDynamicSharedMemorySize, 131072);
    hipFuncSetAttribute((const void*)gemm256<3>,
                        hipFuncAttributeMaxDynamicSharedMemorySize, 131072);

    // LN1: x -> Ybf + xb(bf16 copy of x, into x1's buffer), then transpose
    ln_f32<<<12544, 256, 0, stream>>>(x, ln1_g, ln1_b, Ybf, x1);
    transp_k<<<dim3(49, 12, 16), 256, 0, stream>>>(Ybf, Xt);

    // fused K/Q/V projection (N padded 1920->2048), split-store raw K/Q/V
    gemm256<0><<<dim3(8, 196), 512, 131072, stream>>>(
        Xt, Wkqv_bf, bkqv, nullptr, Kt, Qt, Vt, 50176, 2048, 768);

    // attention middle: exp-fused context + (normalize in att_k) + softmax-fused att
    hipMemsetAsync(ctx, 0, 2359296 + 49152, stream);
    context_k<<<dim3(14, 128), 256, 0, stream>>>(Kt, Vt, ctx, Sf);
    att_k<<<dim3(13, 128), 256, 0, stream>>>(ctx, Sf, Qt, attb);

    // Wr projection as one 256^2 GEMM over all tokens (resid aliases C0)
    gemm256<1><<<dim3(3, 196), 512, 131072, stream>>>(
        attb, Wr_bf, br, x1, x1, nullptr, nullptr, 50176, 768, 384);

    // LN2: x1 -> Y2bf (wave-per-token)
    ln_bf<<<12544, 256, 0, stream>>>(x1, ln2_g, ln2_b, Y2bf);

    // MLP1: [50176,3072] = Y2 @ W1^T, +b1, gelu, bf16
    gemm256<2><<<dim3(12, 196), 512, 131072, stream>>>(
        Y2bf, W1_bf, b1, nullptr, Hbf, nullptr, nullptr, 50176, 3072, 768);
    // MLP2: d_out(f32) = H @ W2^T + b2 + x1
    gemm256<3><<<dim3(3, 196), 512, 131072, stream>>>(
        Hbf, W2_bf, b2, x1, d_out, nullptr, nullptr, 50176, 768, 3072);
}

// Round 14
// 1385.847 us; speedup vs baseline: 1.0368x; 1.0368x over previous
//
#include <hip/hip_runtime.h>
#include <hip/hip_bf16.h>

using bf16 = __hip_bfloat16;
typedef __attribute__((ext_vector_type(8))) short short8;
typedef __attribute__((ext_vector_type(4))) short short4v;
typedef __attribute__((ext_vector_type(4))) float f32x4;

__device__ __forceinline__ float bfbits2f(unsigned short h) {
    unsigned v = (unsigned)h << 16;
    return __uint_as_float(v);
}

__device__ __forceinline__ void gload16(const void* g, void* l) {
    __builtin_amdgcn_global_load_lds(
        (const __attribute__((address_space(1))) unsigned int*)g,
        (__attribute__((address_space(3))) unsigned int*)l, 16, 0, 0);
}

// tanh-form GELU: ~8 VALU; |diff vs exact erf-GELU| <= ~3e-3
__device__ __forceinline__ float gelu_fast(float x) {
    float x2 = x * x;
    float u = x * __builtin_fmaf(0.07135481f, x2, 1.59576912f);
    float e = __expf(u);
    return x - x * __builtin_amdgcn_rcpf(e + 1.0f);
}

__device__ __forceinline__ float wave_sum(float v) {
#pragma unroll
    for (int o = 32; o > 0; o >>= 1) v += __shfl_xor(v, o, 64);
    return v;
}

// ---- LayerNorm over D=768: one WAVE per token; also emits bf16 copy of x ----
__global__ __launch_bounds__(256) void ln_f32(const float* __restrict__ x,
                                              const float* __restrict__ g,
                                              const float* __restrict__ b,
                                              bf16* __restrict__ y,
                                              bf16* __restrict__ xb) {
    int wave = threadIdx.x >> 6, lane = threadIdx.x & 63;
    size_t base = ((size_t)blockIdx.x * 4 + wave) * 768;
    int c0 = lane * 4;
    float4 v0 = *(const float4*)&x[base + c0];
    float4 v1 = *(const float4*)&x[base + 256 + c0];
    float4 v2 = *(const float4*)&x[base + 512 + c0];
    float raw[12] = {v0.x, v0.y, v0.z, v0.w, v1.x, v1.y, v1.z, v1.w,
                     v2.x, v2.y, v2.z, v2.w};
#pragma unroll
    for (int j = 0; j < 3; j++) {
        short4v o;
#pragma unroll
        for (int u = 0; u < 4; u++)
            o[u] = (short)__bfloat16_as_ushort(__float2bfloat16(raw[j * 4 + u]));
        *(short4v*)&((unsigned short*)xb)[base + j * 256 + c0] = o;
    }
    float s = wave_sum(v0.x + v0.y + v0.z + v0.w + v1.x + v1.y + v1.z + v1.w +
                       v2.x + v2.y + v2.z + v2.w);
    float mean = s * (1.0f / 768.0f);
    float d[12];
#pragma unroll
    for (int i = 0; i < 12; i++) d[i] = raw[i] - mean;
    float sq = 0.f;
#pragma unroll
    for (int i = 0; i < 12; i++) sq += d[i] * d[i];
    sq = wave_sum(sq);
    float rstd = rsqrtf(sq * (1.0f / 768.0f) + 1e-6f);
#pragma unroll
    for (int j = 0; j < 3; j++) {
        float4 gv = *(const float4*)&g[j * 256 + c0];
        float4 bv = *(const float4*)&b[j * 256 + c0];
        short4v o;
        o[0] = (short)__bfloat16_as_ushort(__float2bfloat16(d[j * 4 + 0] * rstd * gv.x + bv.x));
        o[1] = (short)__bfloat16_as_ushort(__float2bfloat16(d[j * 4 + 1] * rstd * gv.y + bv.y));
        o[2] = (short)__bfloat16_as_ushort(__float2bfloat16(d[j * 4 + 2] * rstd * gv.z + bv.z));
        o[3] = (short)__bfloat16_as_ushort(__float2bfloat16(d[j * 4 + 3] * rstd * gv.w + bv.w));
        *(short4v*)&((unsigned short*)y)[base + j * 256 + c0] = o;
    }
}

// ---- LayerNorm, bf16 in -> bf16 out (wave-per-token) ----
__global__ __launch_bounds__(256) void ln_bf(const bf16* __restrict__ x,
                                             const float* __restrict__ g,
                                             const float* __restrict__ b,
                                             bf16* __restrict__ y) {
    int wave = threadIdx.x >> 6, lane = threadIdx.x & 63;
    size_t base = ((size_t)blockIdx.x * 4 + wave) * 768;
    int c0 = lane * 4;
    float d[12];
#pragma unroll
    for (int j = 0; j < 3; j++) {
        short4v w = *(const short4v*)&((const unsigned short*)x)[base + j * 256 + c0];
#pragma unroll
        for (int u = 0; u < 4; u++) d[j * 4 + u] = bfbits2f((unsigned short)w[u]);
    }
    float s = 0.f;
#pragma unroll
    for (int i = 0; i < 12; i++) s += d[i];
    s = wave_sum(s);
    float mean = s * (1.0f / 768.0f);
    float sq = 0.f;
#pragma unroll
    for (int i = 0; i < 12; i++) { d[i] -= mean; sq += d[i] * d[i]; }
    sq = wave_sum(sq);
    float rstd = rsqrtf(sq * (1.0f / 768.0f) + 1e-6f);
#pragma unroll
    for (int j = 0; j < 3; j++) {
        float4 gv = *(const float4*)&g[j * 256 + c0];
        float4 bv = *(const float4*)&b[j * 256 + c0];
        short4v o;
        o[0] = (short)__bfloat16_as_ushort(__float2bfloat16(d[j * 4 + 0] * rstd * gv.x + bv.x));
        o[1] = (short)__bfloat16_as_ushort(__float2bfloat16(d[j * 4 + 1] * rstd * gv.y + bv.y));
        o[2] = (short)__bfloat16_as_ushort(__float2bfloat16(d[j * 4 + 2] * rstd * gv.z + bv.z));
        o[3] = (short)__bfloat16_as_ushort(__float2bfloat16(d[j * 4 + 3] * rstd * gv.w + bv.w));
        *(short4v*)&((unsigned short*)y)[base + j * 256 + c0] = o;
    }
}

// ---- fused prep: weight casts (+KQV pad-zero) + bias concat, one launch ----
__global__ __launch_bounds__(256) void prep(
    const float* __restrict__ Wk, const float* __restrict__ Wq,
    const float* __restrict__ Wv, const float* __restrict__ Wr,
    const float* __restrict__ W1, const float* __restrict__ W2,
    const float* __restrict__ bk, const float* __restrict__ bq,
    const float* __restrict__ bv,
    bf16* __restrict__ Wkqv, bf16* __restrict__ Wrb,
    bf16* __restrict__ W1b, bf16* __restrict__ W2b, float* __restrict__ bkqv) {
    int i = blockIdx.x * 256 + threadIdx.x;
    const int nKQV = 2048 * 768, nWr = 768 * 384, nW1 = 3072 * 768, nW2 = 768 * 3072;
    if (i < nKQV) {
        int r = i / 768;
        float v = 0.f;
        if (r < 768) v = Wk[i];
        else if (r < 1536) v = Wq[i - 768 * 768];
        else if (r < 1920) v = Wv[i - 1536 * 768];
        Wkqv[i] = __float2bfloat16(v);
        return;
    }
    i -= nKQV;
    if (i < nWr) { Wrb[i] = __float2bfloat16(Wr[i]); return; }
    i -= nWr;
    if (i < nW1) { W1b[i] = __float2bfloat16(W1[i]); return; }
    i -= nW1;
    if (i < nW2) { W2b[i] = __float2bfloat16(W2[i]); return; }
    i -= nW2;
    if (i < 1920) bkqv[i] = (i < 768) ? bk[i] : (i < 1536 ? bq[i - 768] : bv[i - 1536]);
}

// ---- bf16 transpose per batch: Y [768,3136] -> Xt [3136,768] ----
__global__ __launch_bounds__(256) void transp_k(const bf16* __restrict__ Y,
                                                bf16* __restrict__ Xt) {
    __shared__ unsigned short tile[64][65];
    const size_t LD = (size_t)768 * 3136;
    int n = blockIdx.z;
    int l0 = blockIdx.x * 64, d0 = blockIdx.y * 64;
    const unsigned short* Yp = (const unsigned short*)Y + (size_t)n * LD;
    unsigned short* Xp = (unsigned short*)Xt + (size_t)n * LD;
    int t = threadIdx.x;
#pragma unroll
    for (int j = 0; j < 2; j++) {
        int e = t + 256 * j;
        int dd = e >> 3, lg = (e & 7) * 8;
        short8 v = *(const short8*)&Yp[(size_t)(d0 + dd) * 3136 + l0 + lg];
#pragma unroll
        for (int u = 0; u < 8; u++) tile[dd][lg + u] = (unsigned short)v[u];
    }
    __syncthreads();
#pragma unroll
    for (int j = 0; j < 2; j++) {
        int e = t + 256 * j;
        int ll = e >> 3, dg = (e & 7) * 8;
        short8 v;
#pragma unroll
        for (int u = 0; u < 8; u++) v[u] = (short)tile[dg + u][ll];
        *(short8*)&Xp[(size_t)(l0 + ll) * 768 + d0 + dg] = v;
    }
}

// ====== 256x256 BK=64 GEMM, 4-phase/tile interleave + counted vmcnt ======
// Schedule byte-identical to R9-R12.
// MODE 0: split-KQV bf16 (N padded; store col<1920), +bias[col]
// MODE 1: C0=bf16, v + bias[col] + residb(bf16)[flat]  (Wr; resid aliases C0)
// MODE 2: C0=bf16, gelu(v + bias[col])
// MODE 3: C0=f32,  v + bias[col] + residb(bf16)[flat]
template <int MODE>
__global__ __launch_bounds__(512, 2) void gemm256(
    const bf16* __restrict__ A, const bf16* __restrict__ B,
    const float* __restrict__ bias, const void* __restrict__ resid,
    void* __restrict__ C0, void* __restrict__ C1, void* __restrict__ C2,
    int M, int N, int K) {
    extern __shared__ char smem[];
    const int tid = threadIdx.x;
    const int lane = tid & 63, wave = tid >> 6;

    const int nbn = gridDim.x;
    const int nwg = nbn * gridDim.y;
    const int orig = blockIdx.y * nbn + blockIdx.x;
    const int qq = nwg >> 3, rm = nwg & 7;
    const int xcd = orig & 7, pos = orig >> 3;
    const int work = (xcd < rm ? xcd * (qq + 1) : rm * (qq + 1) + (xcd - rm) * qq) + pos;
    const int bn = work % nbn, bm = work / nbn;

    const int wm = (wave >> 2) * 128, wn = (wave & 3) * 64;
    const int frow = lane & 15, fsb = lane >> 4;
    const int rslot = (fsb ^ ((frow >> 1) & 3)) * 16;
    const int srowS = lane >> 2;
    const int sslotS = (lane & 3) ^ ((lane >> 3) & 3);
    const size_t rowB = (size_t)K * 2;
    const char* ApS = (const char*)A + (size_t)(bm * 256 + wave * 32 + srowS) * rowB + sslotS * 16;
    const char* BpS = (const char*)B + (size_t)(bn * 256 + wave * 32 + srowS) * rowB + sslotS * 16;

    f32x4 acc[8][4];
#pragma unroll
    for (int mi = 0; mi < 8; mi++)
#pragma unroll
        for (int ni = 0; ni < 4; ni++)
#pragma unroll
            for (int r = 0; r < 4; r++) acc[mi][ni][r] = 0.0f;

    auto stA = [&](int t, int k2) {
        char* d = smem + (t & 1) * 65536 + k2 * 16384 + wave * 2048;
        const char* s = ApS + (size_t)t * 128 + k2 * 64;
        gload16(s, d);
        gload16(s + (size_t)16 * rowB, d + 1024);
    };
    auto stB = [&](int t, int k2) {
        char* d = smem + (t & 1) * 65536 + 32768 + k2 * 16384 + wave * 2048;
        const char* s = BpS + (size_t)t * 128 + k2 * 64;
        gload16(s, d);
        gload16(s + (size_t)16 * rowB, d + 1024);
    };

    const int nt = K >> 6;
    stA(0, 0); stB(0, 0); stA(0, 1); stB(0, 1);
    stA(1, 0); stB(1, 0);
    asm volatile("s_waitcnt vmcnt(8)" ::: "memory");
    __builtin_amdgcn_s_barrier();
    asm volatile("" ::: "memory");

    for (int t = 0; t < nt; ++t) {
        const char* base = smem + (t & 1) * 65536;
        short8 bfv[4], af[4];
        // ---------- phase 0: k2=0, M-low ----------
#pragma unroll
        for (int ni = 0; ni < 4; ni++)
            bfv[ni] = *(const short8*)(base + 32768 + (wn + ni * 16 + frow) * 64 + rslot);
#pragma unroll
        for (int i = 0; i < 4; i++)
            af[i] = *(const short8*)(base + (wm + i * 16 + frow) * 64 + rslot);
        if (t + 1 < nt) stA(t + 1, 1);
        asm volatile("" ::: "memory");
        __builtin_amdgcn_s_barrier();
        asm volatile("" ::: "memory");
        __builtin_amdgcn_s_setprio(1);
#pragma unroll
        for (int i = 0; i < 4; i++)
#pragma unroll
            for (int ni = 0; ni < 4; ni++)
                acc[i][ni] = __builtin_amdgcn_mfma_f32_16x16x32_bf16(
                    af[i], bfv[ni], acc[i][ni], 0, 0, 0);
        __builtin_amdgcn_s_setprio(0);
        asm volatile("" ::: "memory");
        __builtin_amdgcn_s_barrier();
        asm volatile("" ::: "memory");
        // ---------- phase 1: k2=0, M-high ----------
#pragma unroll
        for (int i = 0; i < 4; i++)
            af[i] = *(const short8*)(base + (wm + (4 + i) * 16 + frow) * 64 + rslot);
        if (t + 1 < nt) stB(t + 1, 1);
        asm volatile("" ::: "memory");
        __builtin_amdgcn_s_barrier();
        asm volatile("" ::: "memory");
        __builtin_amdgcn_s_setprio(1);
#pragma unroll
        for (int i = 0; i < 4; i++)
#pragma unroll
            for (int ni = 0; ni < 4; ni++)
                acc[4 + i][ni] = __builtin_amdgcn_mfma_f32_16x16x32_bf16(
                    af[i], bfv[ni], acc[4 + i][ni], 0, 0, 0);
        __builtin_amdgcn_s_setprio(0);
        if (t == nt - 1)
            asm volatile("s_waitcnt vmcnt(0)" ::: "memory");
        else
            asm volatile("s_waitcnt vmcnt(8)" ::: "memory");
        __builtin_amdgcn_s_barrier();
        asm volatile("" ::: "memory");
        // ---------- phase 2: k2=1, M-low ----------
#pragma unroll
        for (int ni = 0; ni < 4; ni++)
            bfv[ni] = *(const short8*)(base + 32768 + 16384 + (wn + ni * 16 + frow) * 64 + rslot);
#pragma unroll
        for (int i = 0; i < 4; i++)
            af[i] = *(const short8*)(base + 16384 + (wm + i * 16 + frow) * 64 + rslot);
        if (t + 2 < nt) stA(t + 2, 0);
        asm volatile("" ::: "memory");
        __builtin_amdgcn_s_barrier();
        asm volatile("" ::: "memory");
        __builtin_amdgcn_s_setprio(1);
#pragma unroll
        for (int i = 0; i < 4; i++)
#pragma unroll
            for (int ni = 0; ni < 4; ni++)
                acc[i][ni] = __builtin_amdgcn_mfma_f32_16x16x32_bf16(
                    af[i], bfv[ni], acc[i][ni], 0, 0, 0);
        __builtin_amdgcn_s_setprio(0);
        asm volatile("" ::: "memory");
        __builtin_amdgcn_s_barrier();
        asm volatile("" ::: "memory");
        // ---------- phase 3: k2=1, M-high ----------
#pragma unroll
        for (int i = 0; i < 4; i++)
            af[i] = *(const short8*)(base + 16384 + (wm + (4 + i) * 16 + frow) * 64 + rslot);
        if (t + 2 < nt) stB(t + 2, 0);
        asm volatile("" ::: "memory");
        __builtin_amdgcn_s_barrier();
        asm volatile("" ::: "memory");
        __builtin_amdgcn_s_setprio(1);
#pragma unroll
        for (int i = 0; i < 4; i++)
#pragma unroll
            for (int ni = 0; ni < 4; ni++)
                acc[4 + i][ni] = __builtin_amdgcn_mfma_f32_16x16x32_bf16(
                    af[i], bfv[ni], acc[4 + i][ni], 0, 0, 0);
        __builtin_amdgcn_s_setprio(0);
        if (t + 1 < nt) {
            if (t + 1 == nt - 1)
                asm volatile("s_waitcnt vmcnt(4)" ::: "memory");
            else
                asm volatile("s_waitcnt vmcnt(8)" ::: "memory");
        }
        __builtin_amdgcn_s_barrier();
        asm volatile("" ::: "memory");
    }

    const unsigned short* Rb = (const unsigned short*)resid;
#pragma unroll
    for (int mi = 0; mi < 8; mi++)
#pragma unroll
        for (int ni = 0; ni < 4; ni++)
#pragma unroll
            for (int r = 0; r < 4; r++) {
                int row = bm * 256 + wm + mi * 16 + (lane >> 4) * 4 + r;
                int col = bn * 256 + wn + ni * 16 + frow;
                float v = acc[mi][ni][r];
                if (MODE == 0) {
                    if (col < 1920) {
                        float o = v + bias[col];
                        if (col < 768)
                            ((bf16*)C0)[(size_t)row * 768 + col] = __float2bfloat16(o);
                        else if (col < 1536)
                            ((bf16*)C1)[(size_t)row * 768 + col - 768] = __float2bfloat16(o);
                        else
                            ((bf16*)C2)[(size_t)row * 384 + col - 1536] = __float2bfloat16(o);
                    }
                } else if (MODE == 1) {
                    size_t idx = (size_t)row * N + col;
                    ((bf16*)C0)[idx] =
                        __float2bfloat16(v + bias[col] + bfbits2f(Rb[idx]));
                } else if (MODE == 2) {
                    ((bf16*)C0)[(size_t)row * N + col] =
                        __float2bfloat16(gelu_fast(v + bias[col]));
                } else {
                    size_t idx = (size_t)row * N + col;
                    ((float*)C0)[idx] = v + bias[col] + bfbits2f(Rb[idx]);
                }
            }
}

// ---- fused context: ctx_raw[nh,96,48] = sum_l exp(k[l,96]) outer v[l,48];
//      S[nh,96] = sum_l exp(k). Grid (14, 128): 224 l's per block. ----
__global__ __launch_bounds__(256) void context_k(const bf16* __restrict__ Kt,
                                                 const bf16* __restrict__ Vt,
                                                 float* __restrict__ ctx,
                                                 float* __restrict__ Sf) {
    __shared__ float ks[32][96];
    __shared__ float vs[32][48];
    int nh = blockIdx.y;
    int n = nh >> 3, h = nh & 7;
    int t = threadIdx.x;
    const unsigned short* kp = (const unsigned short*)Kt;
    const unsigned short* vp = (const unsigned short*)Vt;
    int a = t >> 4, bq = t & 15;
    float acc[6][3];
    float sacc[6];
#pragma unroll
    for (int i = 0; i < 6; i++) {
        sacc[i] = 0.f;
#pragma unroll
        for (int j = 0; j < 3; j++) acc[i][j] = 0.f;
    }
    int l0 = blockIdx.x * 224;
    for (int ls = l0; ls < l0 + 224; ls += 32) {
        __syncthreads();
#pragma unroll
        for (int j = 0; j < 6; j++) {
            int e = t + 256 * j;
            int row = e / 48, cp = e % 48;
            unsigned u = *(const unsigned*)&kp[((size_t)(n * 3136 + ls + row)) * 768 + h * 96 + cp * 2];
            ks[row][cp * 2] = __expf(bfbits2f((unsigned short)(u & 0xffff)));
            ks[row][cp * 2 + 1] = __expf(bfbits2f((unsigned short)(u >> 16)));
        }
#pragma unroll
        for (int j = 0; j < 3; j++) {
            int e = t + 256 * j;
            int row = e / 24, cp = e % 24;
            unsigned u = *(const unsigned*)&vp[((size_t)(n * 3136 + ls + row)) * 384 + h * 48 + cp * 2];
            vs[row][cp * 2] = bfbits2f((unsigned short)(u & 0xffff));
            vs[row][cp * 2 + 1] = bfbits2f((unsigned short)(u >> 16));
        }
        __syncthreads();
        for (int ll = 0; ll < 32; ll++) {
            float kv[6], vv[3];
#pragma unroll
            for (int i = 0; i < 6; i++) { kv[i] = ks[ll][a * 6 + i]; sacc[i] += kv[i]; }
#pragma unroll
            for (int j = 0; j < 3; j++) vv[j] = vs[ll][bq * 3 + j];
#pragma unroll
            for (int i = 0; i < 6; i++)
#pragma unroll
                for (int j = 0; j < 3; j++) acc[i][j] += kv[i] * vv[j];
        }
    }
    float* cb = ctx + (size_t)nh * 4608;
#pragma unroll
    for (int i = 0; i < 6; i++) {
#pragma unroll
        for (int j = 0; j < 3; j++)
            atomicAdd(&cb[(a * 6 + i) * 48 + bq * 3 + j], acc[i][j]);
        if (bq == 0) atomicAdd(&Sf[(size_t)nh * 96 + a * 6 + i], sacc[i]);
    }
}

// ---- att: normalize ctx by S while loading to LDS, per-token softmax(q),
//      then ctx^T @ q, COMPACT bf16 out [50176, 384] ----
__global__ __launch_bounds__(256) void att_k(const float* __restrict__ ctx,
                                             const float* __restrict__ Sf,
                                             const bf16* __restrict__ Qt,
                                             bf16* __restrict__ att) {
    __shared__ float cs[4608];
    __shared__ float sinv[96];
    int nh = blockIdx.y;
    int n = nh >> 3, h = nh & 7;
    if (threadIdx.x < 96)
        sinv[threadIdx.x] = 1.0f / Sf[(size_t)nh * 96 + threadIdx.x];
    __syncthreads();
    for (int j = threadIdx.x; j < 4608; j += 256)
        cs[j] = ctx[(size_t)nh * 4608 + j] * sinv[j / 48];
    __syncthreads();
    int l = blockIdx.x * 256 + threadIdx.x;
    if (l >= 3136) return;
    const unsigned short* qp = (const unsigned short*)Qt + ((size_t)(n * 3136 + l)) * 768 + h * 96;
    float qv[96];
    float s = 0.f;
#pragma unroll
    for (int j = 0; j < 12; j++) {
        short8 w = *(const short8*)&qp[j * 8];
#pragma unroll
        for (int x = 0; x < 8; x++) {
            float e = __expf(bfbits2f((unsigned short)w[x]));
            qv[j * 8 + x] = e;
            s += e;
        }
    }
    float inv = 1.0f / s;
    unsigned short ov[48];
#pragma unroll
    for (int vb = 0; vb < 12; vb++) {
        f32x4 acc4;
        acc4[0] = acc4[1] = acc4[2] = acc4[3] = 0.f;
        for (int k = 0; k < 96; k++) {
            f32x4 c4 = *(const f32x4*)&cs[k * 48 + vb * 4];
            float q = qv[k];
#pragma unroll
            for (int x = 0; x < 4; x++) acc4[x] += c4[x] * q;
        }
#pragma unroll
        for (int x = 0; x < 4; x++)
            ov[vb * 4 + x] = __bfloat16_as_ushort(__float2bfloat16(acc4[x] * inv));
    }
    unsigned short* op = (unsigned short*)att + ((size_t)(n * 3136 + l)) * 384 + h * 48;
#pragma unroll
    for (int j = 0; j < 6; j++) *(short8*)&op[j * 8] = *(short8*)&ov[j * 8];
}

extern "C" void kernel_launch(void* const* d_in, const int* in_sizes, int n_in,
                              void* d_out, int out_size, void* d_ws, size_t ws_size,
                              hipStream_t stream) {
    (void)in_sizes; (void)n_in; (void)out_size; (void)ws_size;
    const float* x     = (const float*)d_in[0];
    const float* ln1_g = (const float*)d_in[1];
    const float* ln1_b = (const float*)d_in[2];
    const float* Wk    = (const float*)d_in[3];
    const float* bk    = (const float*)d_in[4];
    const float* Wq    = (const float*)d_in[5];
    const float* bq    = (const float*)d_in[6];
    const float* Wv    = (const float*)d_in[7];
    const float* bv    = (const float*)d_in[8];
    const float* Wr    = (const float*)d_in[9];
    const float* br    = (const float*)d_in[10];
    const float* ln2_g = (const float*)d_in[11];
    const float* ln2_b = (const float*)d_in[12];
    const float* W1    = (const float*)d_in[13];
    const float* b1    = (const float*)d_in[14];
    const float* W2    = (const float*)d_in[15];
    const float* b2    = (const float*)d_in[16];

    const size_t sz77 = (size_t)50176 * 768 * 2;

    char* w = (char*)d_ws;
    size_t off = 0;
    auto alloc = [&](size_t bytes) {
        char* p = w + off;
        off = (off + bytes + 255) & ~(size_t)255;
        return p;
    };
    bf16* Ybf  = (bf16*)alloc(sz77);                       // Hbf rgn 0
    bf16* Xt   = (bf16*)alloc(sz77);                       // Hbf rgn 1 (ctx/S alias)
    bf16* Kt   = (bf16*)alloc(sz77);                       // Hbf rgn 2
    bf16* Qt   = (bf16*)alloc(sz77);                       // Hbf rgn 3
    bf16* Vt   = (bf16*)alloc((size_t)50176 * 384 * 2);    // Y2bf rgn (front)
    bf16* attb = (bf16*)alloc((size_t)50176 * 384 * 2);    // Y2bf rgn (back)
    bf16* x1   = (bf16*)alloc(sz77);                       // bf16(x) until Wr overwrites
    bf16* Wkqv_bf = (bf16*)alloc((size_t)2048 * 768 * 2);  // padded to 2048 rows
    bf16* Wr_bf = (bf16*)alloc((size_t)768 * 384 * 2);
    bf16* W1_bf = (bf16*)alloc((size_t)3072 * 768 * 2);
    bf16* W2_bf = (bf16*)alloc((size_t)768 * 3072 * 2);
    float* bkqv = (float*)alloc((size_t)1920 * 4);
    // ctx + S alias Xt (Xt dead after KQV gemm; region dead before MLP1)
    float* ctx = (float*)Xt;
    float* Sf  = (float*)((char*)Xt + 4718592);
    bf16* Hbf  = Ybf;    // [50176,3072] spans rgns 0-3
    bf16* Y2bf = Vt;     // spans Vt+attb exactly

    // fused weight-cast + pad + bias-concat (one launch)
    prep<<<25736, 256, 0, stream>>>(Wk, Wq, Wv, Wr, W1, W2, bk, bq, bv,
                                    Wkqv_bf, Wr_bf, W1_bf, W2_bf, bkqv);

    hipFuncSetAttribute((const void*)gemm256<0>,
                        hipFuncAttributeMaxDynamicSharedMemorySize, 131072);
    hipFuncSetAttribute((const void*)gemm256<1>,
                        hipFuncAttributeMaxDynamicSharedMemorySize, 131072);
    hipFuncSetAttribute((const void*)gemm256<2>,
                        hipFuncAttributeMaxDynamicSharedMemorySize, 131072);
    hipFuncSetAttribute((const void*)gemm256<3>,
                        hipFuncAttributeMaxDynamicSharedMemorySize, 131072);

    // LN1: x -> Ybf + xb(bf16 copy of x, into x1's buffer), then transpose
    ln_f32<<<12544, 256, 0, stream>>>(x, ln1_g, ln1_b, Ybf, x1);
    transp_k<<<dim3(49, 12, 16), 256, 0, stream>>>(Ybf, Xt);

    // fused K/Q/V projection (N padded 1920->2048), split-store raw K/Q/V
    gemm256<0><<<dim3(8, 196), 512, 131072, stream>>>(
        Xt, Wkqv_bf, bkqv, nullptr, Kt, Qt, Vt, 50176, 2048, 768);

    // attention middle: exp-fused context + (normalize in att_k) + softmax-fused att
    hipMemsetAsync(ctx, 0, 4718592 + 49152, stream);
    context_k<<<dim3(14, 128), 256, 0, stream>>>(Kt, Vt, ctx, Sf);
    att_k<<<dim3(13, 128), 256, 0, stream>>>(ctx, Sf, Qt, attb);

    // Wr projection as one 256^2 GEMM over all tokens (resid aliases C0)
    gemm256<1><<<dim3(3, 196), 512, 131072, stream>>>(
        attb, Wr_bf, br, x1, x1, nullptr, nullptr, 50176, 768, 384);

    // LN2: x1 -> Y2bf (wave-per-token)
    ln_bf<<<12544, 256, 0, stream>>>(x1, ln2_g, ln2_b, Y2bf);

    // MLP1: [50176,3072] = Y2 @ W1^T, +b1, gelu, bf16
    gemm256<2><<<dim3(12, 196), 512, 131072, stream>>>(
        Y2bf, W1_bf, b1, nullptr, Hbf, nullptr, nullptr, 50176, 3072, 768);
    // MLP2: d_out(f32) = H @ W2^T + b2 + x1
    gemm256<3><<<dim3(3, 196), 512, 131072, stream>>>(
        Hbf, W2_bf, b2, x1, d_out, nullptr, nullptr, 50176, 768, 3072);
}

// Round 15
// 1382.193 us; speedup vs baseline: 1.0396x; 1.0026x over previous
//
#include <hip/hip_runtime.h>
#include <hip/hip_bf16.h>

using bf16 = __hip_bfloat16;
typedef __attribute__((ext_vector_type(8))) short short8;
typedef __attribute__((ext_vector_type(4))) short short4v;
typedef __attribute__((ext_vector_type(4))) float f32x4;

__device__ __forceinline__ float bfbits2f(unsigned short h) {
    unsigned v = (unsigned)h << 16;
    return __uint_as_float(v);
}

__device__ __forceinline__ void gload16(const void* g, void* l) {
    __builtin_amdgcn_global_load_lds(
        (const __attribute__((address_space(1))) unsigned int*)g,
        (__attribute__((address_space(3))) unsigned int*)l, 16, 0, 0);
}

// tanh-form GELU: ~8 VALU; |diff vs exact erf-GELU| <= ~3e-3
__device__ __forceinline__ float gelu_fast(float x) {
    float x2 = x * x;
    float u = x * __builtin_fmaf(0.07135481f, x2, 1.59576912f);
    float e = __expf(u);
    return x - x * __builtin_amdgcn_rcpf(e + 1.0f);
}

__device__ __forceinline__ float wave_sum(float v) {
#pragma unroll
    for (int o = 32; o > 0; o >>= 1) v += __shfl_xor(v, o, 64);
    return v;
}

// ---- LayerNorm over D=768: one WAVE per token; also emits bf16 copy of x ----
__global__ __launch_bounds__(256) void ln_f32(const float* __restrict__ x,
                                              const float* __restrict__ g,
                                              const float* __restrict__ b,
                                              bf16* __restrict__ y,
                                              bf16* __restrict__ xb) {
    int wave = threadIdx.x >> 6, lane = threadIdx.x & 63;
    size_t base = ((size_t)blockIdx.x * 4 + wave) * 768;
    int c0 = lane * 4;
    float4 v0 = *(const float4*)&x[base + c0];
    float4 v1 = *(const float4*)&x[base + 256 + c0];
    float4 v2 = *(const float4*)&x[base + 512 + c0];
    float raw[12] = {v0.x, v0.y, v0.z, v0.w, v1.x, v1.y, v1.z, v1.w,
                     v2.x, v2.y, v2.z, v2.w};
#pragma unroll
    for (int j = 0; j < 3; j++) {
        short4v o;
#pragma unroll
        for (int u = 0; u < 4; u++)
            o[u] = (short)__bfloat16_as_ushort(__float2bfloat16(raw[j * 4 + u]));
        *(short4v*)&((unsigned short*)xb)[base + j * 256 + c0] = o;
    }
    float s = wave_sum(v0.x + v0.y + v0.z + v0.w + v1.x + v1.y + v1.z + v1.w +
                       v2.x + v2.y + v2.z + v2.w);
    float mean = s * (1.0f / 768.0f);
    float d[12];
#pragma unroll
    for (int i = 0; i < 12; i++) d[i] = raw[i] - mean;
    float sq = 0.f;
#pragma unroll
    for (int i = 0; i < 12; i++) sq += d[i] * d[i];
    sq = wave_sum(sq);
    float rstd = rsqrtf(sq * (1.0f / 768.0f) + 1e-6f);
#pragma unroll
    for (int j = 0; j < 3; j++) {
        float4 gv = *(const float4*)&g[j * 256 + c0];
        float4 bv = *(const float4*)&b[j * 256 + c0];
        short4v o;
        o[0] = (short)__bfloat16_as_ushort(__float2bfloat16(d[j * 4 + 0] * rstd * gv.x + bv.x));
        o[1] = (short)__bfloat16_as_ushort(__float2bfloat16(d[j * 4 + 1] * rstd * gv.y + bv.y));
        o[2] = (short)__bfloat16_as_ushort(__float2bfloat16(d[j * 4 + 2] * rstd * gv.z + bv.z));
        o[3] = (short)__bfloat16_as_ushort(__float2bfloat16(d[j * 4 + 3] * rstd * gv.w + bv.w));
        *(short4v*)&((unsigned short*)y)[base + j * 256 + c0] = o;
    }
}

// ---- LayerNorm, bf16 in -> bf16 out (wave-per-token) ----
__global__ __launch_bounds__(256) void ln_bf(const bf16* __restrict__ x,
                                             const float* __restrict__ g,
                                             const float* __restrict__ b,
                                             bf16* __restrict__ y) {
    int wave = threadIdx.x >> 6, lane = threadIdx.x & 63;
    size_t base = ((size_t)blockIdx.x * 4 + wave) * 768;
    int c0 = lane * 4;
    float d[12];
#pragma unroll
    for (int j = 0; j < 3; j++) {
        short4v w = *(const short4v*)&((const unsigned short*)x)[base + j * 256 + c0];
#pragma unroll
        for (int u = 0; u < 4; u++) d[j * 4 + u] = bfbits2f((unsigned short)w[u]);
    }
    float s = 0.f;
#pragma unroll
    for (int i = 0; i < 12; i++) s += d[i];
    s = wave_sum(s);
    float mean = s * (1.0f / 768.0f);
    float sq = 0.f;
#pragma unroll
    for (int i = 0; i < 12; i++) { d[i] -= mean; sq += d[i] * d[i]; }
    sq = wave_sum(sq);
    float rstd = rsqrtf(sq * (1.0f / 768.0f) + 1e-6f);
#pragma unroll
    for (int j = 0; j < 3; j++) {
        float4 gv = *(const float4*)&g[j * 256 + c0];
        float4 bv = *(const float4*)&b[j * 256 + c0];
        short4v o;
        o[0] = (short)__bfloat16_as_ushort(__float2bfloat16(d[j * 4 + 0] * rstd * gv.x + bv.x));
        o[1] = (short)__bfloat16_as_ushort(__float2bfloat16(d[j * 4 + 1] * rstd * gv.y + bv.y));
        o[2] = (short)__bfloat16_as_ushort(__float2bfloat16(d[j * 4 + 2] * rstd * gv.z + bv.z));
        o[3] = (short)__bfloat16_as_ushort(__float2bfloat16(d[j * 4 + 3] * rstd * gv.w + bv.w));
        *(short4v*)&((unsigned short*)y)[base + j * 256 + c0] = o;
    }
}

// ---- fused prep, VECTORIZED x4: weight casts (+KQV pad) + bias concat ----
// element ranges (in float4 units): KQV 393216 | Wr 73728 | W1 589824 | W2 589824
__global__ __launch_bounds__(256) void prep(
    const float* __restrict__ Wk, const float* __restrict__ Wq,
    const float* __restrict__ Wv, const float* __restrict__ Wr,
    const float* __restrict__ W1, const float* __restrict__ W2,
    const float* __restrict__ bk, const float* __restrict__ bq,
    const float* __restrict__ bv,
    bf16* __restrict__ Wkqv, bf16* __restrict__ Wrb,
    bf16* __restrict__ W1b, bf16* __restrict__ W2b, float* __restrict__ bkqv) {
    int q = blockIdx.x * 256 + threadIdx.x;   // float4 index
    const int nKQV = 2048 * 768 / 4, nWr = 768 * 384 / 4;
    const int nW1 = 3072 * 768 / 4, nW2 = 768 * 3072 / 4;
    auto cvt = [](float4 v) {
        short4v o;
        o[0] = (short)__bfloat16_as_ushort(__float2bfloat16(v.x));
        o[1] = (short)__bfloat16_as_ushort(__float2bfloat16(v.y));
        o[2] = (short)__bfloat16_as_ushort(__float2bfloat16(v.z));
        o[3] = (short)__bfloat16_as_ushort(__float2bfloat16(v.w));
        return o;
    };
    if (q < nKQV) {
        int i = q * 4;
        int r = i / 768;     // 4 elems stay within one row (768 % 4 == 0)
        float4 v = {0.f, 0.f, 0.f, 0.f};
        if (r < 768) v = *(const float4*)&Wk[i];
        else if (r < 1536) v = *(const float4*)&Wq[i - 768 * 768];
        else if (r < 1920) v = *(const float4*)&Wv[i - 1536 * 768];
        *(short4v*)&((unsigned short*)Wkqv)[i] = cvt(v);
        return;
    }
    q -= nKQV;
    if (q < nWr) {
        *(short4v*)&((unsigned short*)Wrb)[q * 4] = cvt(*(const float4*)&Wr[q * 4]);
        return;
    }
    q -= nWr;
    if (q < nW1) {
        *(short4v*)&((unsigned short*)W1b)[q * 4] = cvt(*(const float4*)&W1[q * 4]);
        return;
    }
    q -= nW1;
    if (q < nW2) {
        *(short4v*)&((unsigned short*)W2b)[q * 4] = cvt(*(const float4*)&W2[q * 4]);
        return;
    }
    q -= nW2;
    if (q < 480) {
        int i = q * 4;
        float4 v;
        if (i < 768) v = *(const float4*)&bk[i];
        else if (i < 1536) v = *(const float4*)&bq[i - 768];
        else v = *(const float4*)&bv[i - 1536];
        *(float4*)&bkqv[i] = v;
    }
}

// ---- bf16 transpose per batch: Y [768,3136] -> Xt [3136,768] ----
__global__ __launch_bounds__(256) void transp_k(const bf16* __restrict__ Y,
                                                bf16* __restrict__ Xt) {
    __shared__ unsigned short tile[64][65];
    const size_t LD = (size_t)768 * 3136;
    int n = blockIdx.z;
    int l0 = blockIdx.x * 64, d0 = blockIdx.y * 64;
    const unsigned short* Yp = (const unsigned short*)Y + (size_t)n * LD;
    unsigned short* Xp = (unsigned short*)Xt + (size_t)n * LD;
    int t = threadIdx.x;
#pragma unroll
    for (int j = 0; j < 2; j++) {
        int e = t + 256 * j;
        int dd = e >> 3, lg = (e & 7) * 8;
        short8 v = *(const short8*)&Yp[(size_t)(d0 + dd) * 3136 + l0 + lg];
#pragma unroll
        for (int u = 0; u < 8; u++) tile[dd][lg + u] = (unsigned short)v[u];
    }
    __syncthreads();
#pragma unroll
    for (int j = 0; j < 2; j++) {
        int e = t + 256 * j;
        int ll = e >> 3, dg = (e & 7) * 8;
        short8 v;
#pragma unroll
        for (int u = 0; u < 8; u++) v[u] = (short)tile[dg + u][ll];
        *(short8*)&Xp[(size_t)(l0 + ll) * 768 + d0 + dg] = v;
    }
}

// ====== 256x256 BK=64 GEMM, 4-phase/tile interleave + counted vmcnt ======
// Schedule byte-identical to R9-R14.
// MODE 0: split-KQV bf16 (N padded; store col<1920), +bias[col]
// MODE 1: C0=bf16, v + bias[col] + residb(bf16)[flat]  (Wr; resid aliases C0)
// MODE 2: C0=bf16, gelu(v + bias[col])
// MODE 3: C0=f32,  v + bias[col] + residb(bf16)[flat]
template <int MODE>
__global__ __launch_bounds__(512, 2) void gemm256(
    const bf16* __restrict__ A, const bf16* __restrict__ B,
    const float* __restrict__ bias, const void* __restrict__ resid,
    void* __restrict__ C0, void* __restrict__ C1, void* __restrict__ C2,
    int M, int N, int K) {
    extern __shared__ char smem[];
    const int tid = threadIdx.x;
    const int lane = tid & 63, wave = tid >> 6;

    const int nbn = gridDim.x;
    const int nwg = nbn * gridDim.y;
    const int orig = blockIdx.y * nbn + blockIdx.x;
    const int qq = nwg >> 3, rm = nwg & 7;
    const int xcd = orig & 7, pos = orig >> 3;
    const int work = (xcd < rm ? xcd * (qq + 1) : rm * (qq + 1) + (xcd - rm) * qq) + pos;
    const int bn = work % nbn, bm = work / nbn;

    const int wm = (wave >> 2) * 128, wn = (wave & 3) * 64;
    const int frow = lane & 15, fsb = lane >> 4;
    const int rslot = (fsb ^ ((frow >> 1) & 3)) * 16;
    const int srowS = lane >> 2;
    const int sslotS = (lane & 3) ^ ((lane >> 3) & 3);
    const size_t rowB = (size_t)K * 2;
    const char* ApS = (const char*)A + (size_t)(bm * 256 + wave * 32 + srowS) * rowB + sslotS * 16;
    const char* BpS = (const char*)B + (size_t)(bn * 256 + wave * 32 + srowS) * rowB + sslotS * 16;

    f32x4 acc[8][4];
#pragma unroll
    for (int mi = 0; mi < 8; mi++)
#pragma unroll
        for (int ni = 0; ni < 4; ni++)
#pragma unroll
            for (int r = 0; r < 4; r++) acc[mi][ni][r] = 0.0f;

    auto stA = [&](int t, int k2) {
        char* d = smem + (t & 1) * 65536 + k2 * 16384 + wave * 2048;
        const char* s = ApS + (size_t)t * 128 + k2 * 64;
        gload16(s, d);
        gload16(s + (size_t)16 * rowB, d + 1024);
    };
    auto stB = [&](int t, int k2) {
        char* d = smem + (t & 1) * 65536 + 32768 + k2 * 16384 + wave * 2048;
        const char* s = BpS + (size_t)t * 128 + k2 * 64;
        gload16(s, d);
        gload16(s + (size_t)16 * rowB, d + 1024);
    };

    const int nt = K >> 6;
    stA(0, 0); stB(0, 0); stA(0, 1); stB(0, 1);
    stA(1, 0); stB(1, 0);
    asm volatile("s_waitcnt vmcnt(8)" ::: "memory");
    __builtin_amdgcn_s_barrier();
    asm volatile("" ::: "memory");

    for (int t = 0; t < nt; ++t) {
        const char* base = smem + (t & 1) * 65536;
        short8 bfv[4], af[4];
        // ---------- phase 0: k2=0, M-low ----------
#pragma unroll
        for (int ni = 0; ni < 4; ni++)
            bfv[ni] = *(const short8*)(base + 32768 + (wn + ni * 16 + frow) * 64 + rslot);
#pragma unroll
        for (int i = 0; i < 4; i++)
            af[i] = *(const short8*)(base + (wm + i * 16 + frow) * 64 + rslot);
        if (t + 1 < nt) stA(t + 1, 1);
        asm volatile("" ::: "memory");
        __builtin_amdgcn_s_barrier();
        asm volatile("" ::: "memory");
        __builtin_amdgcn_s_setprio(1);
#pragma unroll
        for (int i = 0; i < 4; i++)
#pragma unroll
            for (int ni = 0; ni < 4; ni++)
                acc[i][ni] = __builtin_amdgcn_mfma_f32_16x16x32_bf16(
                    af[i], bfv[ni], acc[i][ni], 0, 0, 0);
        __builtin_amdgcn_s_setprio(0);
        asm volatile("" ::: "memory");
        __builtin_amdgcn_s_barrier();
        asm volatile("" ::: "memory");
        // ---------- phase 1: k2=0, M-high ----------
#pragma unroll
        for (int i = 0; i < 4; i++)
            af[i] = *(const short8*)(base + (wm + (4 + i) * 16 + frow) * 64 + rslot);
        if (t + 1 < nt) stB(t + 1, 1);
        asm volatile("" ::: "memory");
        __builtin_amdgcn_s_barrier();
        asm volatile("" ::: "memory");
        __builtin_amdgcn_s_setprio(1);
#pragma unroll
        for (int i = 0; i < 4; i++)
#pragma unroll
            for (int ni = 0; ni < 4; ni++)
                acc[4 + i][ni] = __builtin_amdgcn_mfma_f32_16x16x32_bf16(
                    af[i], bfv[ni], acc[4 + i][ni], 0, 0, 0);
        __builtin_amdgcn_s_setprio(0);
        if (t == nt - 1)
            asm volatile("s_waitcnt vmcnt(0)" ::: "memory");
        else
            asm volatile("s_waitcnt vmcnt(8)" ::: "memory");
        __builtin_amdgcn_s_barrier();
        asm volatile("" ::: "memory");
        // ---------- phase 2: k2=1, M-low ----------
#pragma unroll
        for (int ni = 0; ni < 4; ni++)
            bfv[ni] = *(const short8*)(base + 32768 + 16384 + (wn + ni * 16 + frow) * 64 + rslot);
#pragma unroll
        for (int i = 0; i < 4; i++)
            af[i] = *(const short8*)(base + 16384 + (wm + i * 16 + frow) * 64 + rslot);
        if (t + 2 < nt) stA(t + 2, 0);
        asm volatile("" ::: "memory");
        __builtin_amdgcn_s_barrier();
        asm volatile("" ::: "memory");
        __builtin_amdgcn_s_setprio(1);
#pragma unroll
        for (int i = 0; i < 4; i++)
#pragma unroll
            for (int ni = 0; ni < 4; ni++)
                acc[i][ni] = __builtin_amdgcn_mfma_f32_16x16x32_bf16(
                    af[i], bfv[ni], acc[i][ni], 0, 0, 0);
        __builtin_amdgcn_s_setprio(0);
        asm volatile("" ::: "memory");
        __builtin_amdgcn_s_barrier();
        asm volatile("" ::: "memory");
        // ---------- phase 3: k2=1, M-high ----------
#pragma unroll
        for (int i = 0; i < 4; i++)
            af[i] = *(const short8*)(base + 16384 + (wm + (4 + i) * 16 + frow) * 64 + rslot);
        if (t + 2 < nt) stB(t + 2, 0);
        asm volatile("" ::: "memory");
        __builtin_amdgcn_s_barrier();
        asm volatile("" ::: "memory");
        __builtin_amdgcn_s_setprio(1);
#pragma unroll
        for (int i = 0; i < 4; i++)
#pragma unroll
            for (int ni = 0; ni < 4; ni++)
                acc[4 + i][ni] = __builtin_amdgcn_mfma_f32_16x16x32_bf16(
                    af[i], bfv[ni], acc[4 + i][ni], 0, 0, 0);
        __builtin_amdgcn_s_setprio(0);
        if (t + 1 < nt) {
            if (t + 1 == nt - 1)
                asm volatile("s_waitcnt vmcnt(4)" ::: "memory");
            else
                asm volatile("s_waitcnt vmcnt(8)" ::: "memory");
        }
        __builtin_amdgcn_s_barrier();
        asm volatile("" ::: "memory");
    }

    const unsigned short* Rb = (const unsigned short*)resid;
#pragma unroll
    for (int mi = 0; mi < 8; mi++)
#pragma unroll
        for (int ni = 0; ni < 4; ni++)
#pragma unroll
            for (int r = 0; r < 4; r++) {
                int row = bm * 256 + wm + mi * 16 + (lane >> 4) * 4 + r;
                int col = bn * 256 + wn + ni * 16 + frow;
                float v = acc[mi][ni][r];
                if (MODE == 0) {
                    if (col < 1920) {
                        float o = v + bias[col];
                        if (col < 768)
                            ((bf16*)C0)[(size_t)row * 768 + col] = __float2bfloat16(o);
                        else if (col < 1536)
                            ((bf16*)C1)[(size_t)row * 768 + col - 768] = __float2bfloat16(o);
                        else
                            ((bf16*)C2)[(size_t)row * 384 + col - 1536] = __float2bfloat16(o);
                    }
                } else if (MODE == 1) {
                    size_t idx = (size_t)row * N + col;
                    ((bf16*)C0)[idx] =
                        __float2bfloat16(v + bias[col] + bfbits2f(Rb[idx]));
                } else if (MODE == 2) {
                    ((bf16*)C0)[(size_t)row * N + col] =
                        __float2bfloat16(gelu_fast(v + bias[col]));
                } else {
                    size_t idx = (size_t)row * N + col;
                    ((float*)C0)[idx] = v + bias[col] + bfbits2f(Rb[idx]);
                }
            }
}

// ---- fused context: ctx_raw[nh,96,48] = sum_l exp(k[l,96]) outer v[l,48];
//      S[nh,96] = sum_l exp(k). Grid (14, 128): 224 l's per block. ----
__global__ __launch_bounds__(256) void context_k(const bf16* __restrict__ Kt,
                                                 const bf16* __restrict__ Vt,
                                                 float* __restrict__ ctx,
                                                 float* __restrict__ Sf) {
    __shared__ float ks[32][96];
    __shared__ float vs[32][48];
    int nh = blockIdx.y;
    int n = nh >> 3, h = nh & 7;
    int t = threadIdx.x;
    const unsigned short* kp = (const unsigned short*)Kt;
    const unsigned short* vp = (const unsigned short*)Vt;
    int a = t >> 4, bq = t & 15;
    float acc[6][3];
    float sacc[6];
#pragma unroll
    for (int i = 0; i < 6; i++) {
        sacc[i] = 0.f;
#pragma unroll
        for (int j = 0; j < 3; j++) acc[i][j] = 0.f;
    }
    int l0 = blockIdx.x * 224;
    for (int ls = l0; ls < l0 + 224; ls += 32) {
        __syncthreads();
#pragma unroll
        for (int j = 0; j < 6; j++) {
            int e = t + 256 * j;
            int row = e / 48, cp = e % 48;
            unsigned u = *(const unsigned*)&kp[((size_t)(n * 3136 + ls + row)) * 768 + h * 96 + cp * 2];
            ks[row][cp * 2] = __expf(bfbits2f((unsigned short)(u & 0xffff)));
            ks[row][cp * 2 + 1] = __expf(bfbits2f((unsigned short)(u >> 16)));
        }
#pragma unroll
        for (int j = 0; j < 3; j++) {
            int e = t + 256 * j;
            int row = e / 24, cp = e % 24;
            unsigned u = *(const unsigned*)&vp[((size_t)(n * 3136 + ls + row)) * 384 + h * 48 + cp * 2];
            vs[row][cp * 2] = bfbits2f((unsigned short)(u & 0xffff));
            vs[row][cp * 2 + 1] = bfbits2f((unsigned short)(u >> 16));
        }
        __syncthreads();
        for (int ll = 0; ll < 32; ll++) {
            float kv[6], vv[3];
#pragma unroll
            for (int i = 0; i < 6; i++) { kv[i] = ks[ll][a * 6 + i]; sacc[i] += kv[i]; }
#pragma unroll
            for (int j = 0; j < 3; j++) vv[j] = vs[ll][bq * 3 + j];
#pragma unroll
            for (int i = 0; i < 6; i++)
#pragma unroll
                for (int j = 0; j < 3; j++) acc[i][j] += kv[i] * vv[j];
        }
    }
    float* cb = ctx + (size_t)nh * 4608;
#pragma unroll
    for (int i = 0; i < 6; i++) {
#pragma unroll
        for (int j = 0; j < 3; j++)
            atomicAdd(&cb[(a * 6 + i) * 48 + bq * 3 + j], acc[i][j]);
        if (bq == 0) atomicAdd(&Sf[(size_t)nh * 96 + a * 6 + i], sacc[i]);
    }
}

// ---- att: normalize ctx by S while loading to LDS, per-token softmax(q),
//      then ctx^T @ q, COMPACT bf16 out [50176, 384] ----
__global__ __launch_bounds__(256) void att_k(const float* __restrict__ ctx,
                                             const float* __restrict__ Sf,
                                             const bf16* __restrict__ Qt,
                                             bf16* __restrict__ att) {
    __shared__ float cs[4608];
    __shared__ float sinv[96];
    int nh = blockIdx.y;
    int n = nh >> 3, h = nh & 7;
    if (threadIdx.x < 96)
        sinv[threadIdx.x] = 1.0f / Sf[(size_t)nh * 96 + threadIdx.x];
    __syncthreads();
    for (int j = threadIdx.x; j < 4608; j += 256)
        cs[j] = ctx[(size_t)nh * 4608 + j] * sinv[j / 48];
    __syncthreads();
    int l = blockIdx.x * 256 + threadIdx.x;
    if (l >= 3136) return;
    const unsigned short* qp = (const unsigned short*)Qt + ((size_t)(n * 3136 + l)) * 768 + h * 96;
    float qv[96];
    float s = 0.f;
#pragma unroll
    for (int j = 0; j < 12; j++) {
        short8 w = *(const short8*)&qp[j * 8];
#pragma unroll
        for (int x = 0; x < 8; x++) {
            float e = __expf(bfbits2f((unsigned short)w[x]));
            qv[j * 8 + x] = e;
            s += e;
        }
    }
    float inv = 1.0f / s;
    unsigned short ov[48];
#pragma unroll
    for (int vb = 0; vb < 12; vb++) {
        f32x4 acc4;
        acc4[0] = acc4[1] = acc4[2] = acc4[3] = 0.f;
        for (int k = 0; k < 96; k++) {
            f32x4 c4 = *(const f32x4*)&cs[k * 48 + vb * 4];
            float q = qv[k];
#pragma unroll
            for (int x = 0; x < 4; x++) acc4[x] += c4[x] * q;
        }
#pragma unroll
        for (int x = 0; x < 4; x++)
            ov[vb * 4 + x] = __bfloat16_as_ushort(__float2bfloat16(acc4[x] * inv));
    }
    unsigned short* op = (unsigned short*)att + ((size_t)(n * 3136 + l)) * 384 + h * 48;
#pragma unroll
    for (int j = 0; j < 6; j++) *(short8*)&op[j * 8] = *(short8*)&ov[j * 8];
}

extern "C" void kernel_launch(void* const* d_in, const int* in_sizes, int n_in,
                              void* d_out, int out_size, void* d_ws, size_t ws_size,
                              hipStream_t stream) {
    (void)in_sizes; (void)n_in; (void)out_size; (void)ws_size;
    const float* x     = (const float*)d_in[0];
    const float* ln1_g = (const float*)d_in[1];
    const float* ln1_b = (const float*)d_in[2];
    const float* Wk    = (const float*)d_in[3];
    const float* bk    = (const float*)d_in[4];
    const float* Wq    = (const float*)d_in[5];
    const float* bq    = (const float*)d_in[6];
    const float* Wv    = (const float*)d_in[7];
    const float* bv    = (const float*)d_in[8];
    const float* Wr    = (const float*)d_in[9];
    const float* br    = (const float*)d_in[10];
    const float* ln2_g = (const float*)d_in[11];
    const float* ln2_b = (const float*)d_in[12];
    const float* W1    = (const float*)d_in[13];
    const float* b1    = (const float*)d_in[14];
    const float* W2    = (const float*)d_in[15];
    const float* b2    = (const float*)d_in[16];

    const size_t sz77 = (size_t)50176 * 768 * 2;

    char* w = (char*)d_ws;
    size_t off = 0;
    auto alloc = [&](size_t bytes) {
        char* p = w + off;
        off = (off + bytes + 255) & ~(size_t)255;
        return p;
    };
    bf16* Ybf  = (bf16*)alloc(sz77);                       // Hbf rgn 0
    bf16* Xt   = (bf16*)alloc(sz77);                       // Hbf rgn 1 (ctx/S alias)
    bf16* Kt   = (bf16*)alloc(sz77);                       // Hbf rgn 2
    bf16* Qt   = (bf16*)alloc(sz77);                       // Hbf rgn 3
    bf16* Vt   = (bf16*)alloc((size_t)50176 * 384 * 2);    // Y2bf rgn (front)
    bf16* attb = (bf16*)alloc((size_t)50176 * 384 * 2);    // Y2bf rgn (back)
    bf16* x1   = (bf16*)alloc(sz77);                       // bf16(x) until Wr overwrites
    bf16* Wkqv_bf = (bf16*)alloc((size_t)2048 * 768 * 2);  // padded to 2048 rows
    bf16* Wr_bf = (bf16*)alloc((size_t)768 * 384 * 2);
    bf16* W1_bf = (bf16*)alloc((size_t)3072 * 768 * 2);
    bf16* W2_bf = (bf16*)alloc((size_t)768 * 3072 * 2);
    float* bkqv = (float*)alloc((size_t)1920 * 4);
    // ctx + S alias Xt (Xt dead after KQV gemm; region dead before MLP1)
    float* ctx = (float*)Xt;
    float* Sf  = (float*)((char*)Xt + 4718592);
    bf16* Hbf  = Ybf;    // [50176,3072] spans rgns 0-3
    bf16* Y2bf = Vt;     // spans Vt+attb exactly

    // fused weight-cast + pad + bias-concat (one launch, float4-vectorized)
    prep<<<6434, 256, 0, stream>>>(Wk, Wq, Wv, Wr, W1, W2, bk, bq, bv,
                                   Wkqv_bf, Wr_bf, W1_bf, W2_bf, bkqv);

    hipFuncSetAttribute((const void*)gemm256<0>,
                        hipFuncAttributeMaxDynamicSharedMemorySize, 131072);
    hipFuncSetAttribute((const void*)gemm256<1>,
                        hipFuncAttributeMaxDynamicSharedMemorySize, 131072);
    hipFuncSetAttribute((const void*)gemm256<2>,
                        hipFuncAttributeMaxDynamicSharedMemorySize, 131072);
    hipFuncSetAttribute((const void*)gemm256<3>,
                        hipFuncAttributeMaxDynamicSharedMemorySize, 131072);

    // LN1: x -> Ybf + xb(bf16 copy of x, into x1's buffer), then transpose
    ln_f32<<<12544, 256, 0, stream>>>(x, ln1_g, ln1_b, Ybf, x1);
    transp_k<<<dim3(49, 12, 16), 256, 0, stream>>>(Ybf, Xt);

    // fused K/Q/V projection (N padded 1920->2048), split-store raw K/Q/V
    gemm256<0><<<dim3(8, 196), 512, 131072, stream>>>(
        Xt, Wkqv_bf, bkqv, nullptr, Kt, Qt, Vt, 50176, 2048, 768);

    // attention middle: exp-fused context + (normalize in att_k) + softmax-fused att
    hipMemsetAsync(ctx, 0, 4718592 + 49152, stream);
    context_k<<<dim3(14, 128), 256, 0, stream>>>(Kt, Vt, ctx, Sf);
    att_k<<<dim3(13, 128), 256, 0, stream>>>(ctx, Sf, Qt, attb);

    // Wr projection as one 256^2 GEMM over all tokens (resid aliases C0)
    gemm256<1><<<dim3(3, 196), 512, 131072, stream>>>(
        attb, Wr_bf, br, x1, x1, nullptr, nullptr, 50176, 768, 384);

    // LN2: x1 -> Y2bf (wave-per-token)
    ln_bf<<<12544, 256, 0, stream>>>(x1, ln2_g, ln2_b, Y2bf);

    // MLP1: [50176,3072] = Y2 @ W1^T, +b1, gelu, bf16
    gemm256<2><<<dim3(12, 196), 512, 131072, stream>>>(
        Y2bf, W1_bf, b1, nullptr, Hbf, nullptr, nullptr, 50176, 3072, 768);
    // MLP2: d_out(f32) = H @ W2^T + b2 + x1
    gemm256<3><<<dim3(3, 196), 512, 131072, stream>>>(
        Hbf, W2_bf, b2, x1, d_out, nullptr, nullptr, 50176, 768, 3072);
}